// Round 1
// baseline (101.985 us; speedup 1.0000x reference)
//
#include <hip/hip_runtime.h>
#include <math.h>

// Problem constants (from reference): B=64, F=240, J=22, 16 segments, 5 paths.
#define BB 64
#define FF 240
#define NJ 22
#define NFRM (BB * FF)

// Kinematic-chain segment tables.
__constant__ int c_seg_s[16] = {2,5,8, 1,4,7, 3,6,9,12, 14,17,19, 13,16,18};
__constant__ int c_seg_e[16] = {5,8,11, 4,7,10, 6,9,12,15, 17,19,21, 16,18,20};
// Path start offset / count within the 16-segment list.
__constant__ int c_po[5] = {0,3,6,10,13};
__constant__ int c_pc[5] = {3,3,4,3,3};

struct F3 { float x, y, z; };
__device__ __forceinline__ F3 sub(F3 a, F3 b){ return {a.x-b.x, a.y-b.y, a.z-b.z}; }
__device__ __forceinline__ F3 crs(F3 a, F3 b){
    return {a.y*b.z - a.z*b.y, a.z*b.x - a.x*b.z, a.x*b.y - a.y*b.x};
}
__device__ __forceinline__ float dt(F3 a, F3 b){ return a.x*b.x + a.y*b.y + a.z*b.z; }
__device__ __forceinline__ F3 snorm(F3 v){
    float ss = dt(v, v);
    if (ss > 0.0f) { float inv = 1.0f / sqrtf(ss); return {v.x*inv, v.y*inv, v.z*inv}; }
    return {0.0f, 0.0f, 0.0f};
}
__device__ __forceinline__ float asin_dot(F3 a, F3 b){
    float d = dt(a, b);
    d = fminf(fmaxf(d, -1.0f), 1.0f);
    return asinf(d);
}

// Gauss linking integral for one segment pair.
__device__ __forceinline__ float gli_pair(F3 s1, F3 e1, F3 s2, F3 e2){
    F3 r13 = sub(s2, s1), r14 = sub(e2, s1);
    F3 r23 = sub(s2, e1), r24 = sub(e2, e1);
    F3 r12 = sub(e1, s1), r34 = sub(e2, s2);
    F3 f0 = snorm(crs(r13, r14));
    F3 f1 = snorm(crs(r14, r24));
    F3 f2 = snorm(crs(r24, r23));
    F3 f3 = snorm(crs(r23, r13));
    float tot = asin_dot(f0, f1) + asin_dot(f1, f2) + asin_dot(f2, f3) + asin_dot(f3, f0);
    float sgn = dt(crs(r34, r12), r13);
    float mult = (sgn <= 0.0f) ? -1.0f : 1.0f;
    return mult * tot * 0.07957747154594767f;  // 1/(4*pi)
}

// Kernel 1: per-frame xz-bbox overlap flag.
__global__ void k_flags(const float* __restrict__ m1, const float* __restrict__ m2,
                        int* __restrict__ flags){
    int idx = blockIdx.x * blockDim.x + threadIdx.x;
    if (idx >= NFRM) return;
    const float* p1 = m1 + (size_t)idx * NJ * 3;
    const float* p2 = m2 + (size_t)idx * NJ * 3;
    float nx1 = 1e30f, xx1 = -1e30f, nz1 = 1e30f, xz1 = -1e30f;
    float nx2 = 1e30f, xx2 = -1e30f, nz2 = 1e30f, xz2 = -1e30f;
    #pragma unroll
    for (int j = 0; j < NJ; ++j){
        float x1 = p1[j*3+0], z1 = p1[j*3+2];
        nx1 = fminf(nx1, x1); xx1 = fmaxf(xx1, x1);
        nz1 = fminf(nz1, z1); xz1 = fmaxf(xz1, z1);
        float x2 = p2[j*3+0], z2 = p2[j*3+2];
        nx2 = fminf(nx2, x2); xx2 = fmaxf(xx2, x2);
        nz2 = fminf(nz2, z2); xz2 = fmaxf(xz2, z2);
    }
    flags[idx] = (xx1 >= nx2 && xx2 >= nx1 && xz1 >= nz2 && xz2 >= nz1) ? 1 : 0;
}

// Kernel 2: one wave per frame; lane l handles pairs p = l + 64k (n = l&15 fixed,
// m = (l>>4) + 4k). 256-pair GLIs -> LDS -> 25-thread reduce into 5x5 path blocks.
__global__ void __launch_bounds__(256) k_gli(const float* __restrict__ m1,
                                             const float* __restrict__ m2,
                                             float* __restrict__ gp){
    __shared__ float pts[4][2][66];   // [wave][motion][joint*3+c]
    __shared__ float g[4][256];       // per-pair GLI
    int tid = threadIdx.x;
    int frame0 = blockIdx.x * 4;

    // Cooperative staging: 4 frames x 2 motions x 66 floats = 528 floats.
    for (int u = tid; u < 528; u += 256){
        int w = u / 132;
        int rem = u - w * 132;
        int mot = rem / 66;
        int r = rem - mot * 66;
        const float* src = mot ? m2 : m1;
        pts[w][mot][r] = src[(size_t)(frame0 + w) * 66 + r];
    }
    __syncthreads();

    int w = tid >> 6, lane = tid & 63;
    int n = lane & 15, q = lane >> 4;
    const float* P1 = pts[w][0];
    const float* P2 = pts[w][1];
    int is2 = c_seg_s[n] * 3, ie2 = c_seg_e[n] * 3;
    F3 s2 = {P2[is2], P2[is2+1], P2[is2+2]};
    F3 e2 = {P2[ie2], P2[ie2+1], P2[ie2+2]};
    #pragma unroll
    for (int k = 0; k < 4; ++k){
        int m = q + 4 * k;
        int is1 = c_seg_s[m] * 3, ie1 = c_seg_e[m] * 3;
        F3 s1 = {P1[is1], P1[is1+1], P1[is1+2]};
        F3 e1 = {P1[ie1], P1[ie1+1], P1[ie1+2]};
        g[w][m * 16 + n] = gli_pair(s1, e1, s2, e2);
    }
    __syncthreads();

    // 4 frames x 25 path-pairs = 100 reducer threads.
    if (tid < 100){
        int w2 = tid / 25, pp = tid - w2 * 25;
        int i = pp / 5, j = pp - i * 5;
        float s = 0.0f;
        for (int a = 0; a < c_pc[i]; ++a)
            for (int b = 0; b < c_pc[j]; ++b)
                s += g[w2][(c_po[i] + a) * 16 + (c_po[j] + b)];
        gp[(size_t)(frame0 + w2) * 25 + pp] = s;
    }
}

// Kernel 3: masked frame-diff, max over 25 path-pairs.
__global__ void k_vel(const float* __restrict__ gp, const int* __restrict__ flags,
                      float* __restrict__ out){
    int idx = blockIdx.x * blockDim.x + threadIdx.x;
    const int total = BB * (FF - 1);
    if (idx >= total) return;
    int b = idx / (FF - 1);
    int f = idx - b * (FF - 1);
    const int* fl = flags + b * FF;

    int v0 = fl[f];
    if (f - 1 >= 0) v0 |= fl[f - 1];
    if (f + 1 < FF) v0 |= fl[f + 1];
    float mk0 = v0 ? 1.0f : 0.0f;

    int f1 = f + 1;
    int v1 = fl[f1];
    v1 |= fl[f1 - 1];
    if (f1 + 1 < FF) v1 |= fl[f1 + 1];
    float mk1 = v1 ? 1.0f : 0.0f;

    const float* g0 = gp + (size_t)(b * FF + f) * 25;
    const float* g1 = g0 + 25;
    float mx = 0.0f;
    #pragma unroll
    for (int p = 0; p < 25; ++p){
        float d = fabsf(g1[p] * mk1 - g0[p] * mk0);
        mx = fmaxf(mx, d);
    }
    out[idx] = mx;
}

extern "C" void kernel_launch(void* const* d_in, const int* in_sizes, int n_in,
                              void* d_out, int out_size, void* d_ws, size_t ws_size,
                              hipStream_t stream) {
    const float* m1 = (const float*)d_in[0];
    const float* m2 = (const float*)d_in[1];
    float* gp   = (float*)d_ws;                                    // NFRM*25 floats
    int*   flags = (int*)((char*)d_ws + (size_t)NFRM * 25 * 4);    // NFRM ints
    float* out = (float*)d_out;

    k_flags<<<(NFRM + 255) / 256, 256, 0, stream>>>(m1, m2, flags);
    k_gli<<<NFRM / 4, 256, 0, stream>>>(m1, m2, gp);
    k_vel<<<(BB * (FF - 1) + 255) / 256, 256, 0, stream>>>(gp, flags, out);
}

// Round 2
// 87.346 us; speedup vs baseline: 1.1676x; 1.1676x over previous
//
#include <hip/hip_runtime.h>
#include <math.h>

// Problem constants: B=64, F=240, J=22, 16 segments, 5 paths.
#define BB 64
#define FF 240
#define NJ 22
#define NFRM (BB * FF)

// Kinematic-chain segment tables.
__constant__ int c_seg_s[16] = {2,5,8, 1,4,7, 3,6,9,12, 14,17,19, 13,16,18};
__constant__ int c_seg_e[16] = {5,8,11, 4,7,10, 6,9,12,15, 17,19,21, 16,18,20};
__constant__ int c_po[5] = {0,3,6,10,13};
__constant__ int c_pc[5] = {3,3,4,3,3};

struct F3 { float x, y, z; };
__device__ __forceinline__ F3 sub(F3 a, F3 b){ return {a.x-b.x, a.y-b.y, a.z-b.z}; }
__device__ __forceinline__ F3 crs(F3 a, F3 b){
    return {fmaf(a.y, b.z, -a.z*b.y), fmaf(a.z, b.x, -a.x*b.z), fmaf(a.x, b.y, -a.y*b.x)};
}
__device__ __forceinline__ float dt(F3 a, F3 b){ return fmaf(a.x, b.x, fmaf(a.y, b.y, a.z*b.z)); }

// Branchless asin, Abramowitz-Stegun 4.4.45 (3-term), |err| <= 6.8e-5 abs.
__device__ __forceinline__ float asin_fast(float d){
    float ax = fabsf(d);
    float p = fmaf(fmaf(fmaf(-0.0187293f, ax, 0.0742610f), ax, -0.2121144f), ax, 1.5707288f);
    float r = 1.57079632679f - sqrtf(1.0f - ax) * p;
    return copysignf(r, d);
}

// Gauss linking integral for one segment pair (unnormalized-f formulation).
__device__ __forceinline__ float gli_pair(F3 s1, F3 e1, F3 s2, F3 e2){
    F3 r13 = sub(s2, s1), r14 = sub(e2, s1);
    F3 r23 = sub(s2, e1), r24 = sub(e2, e1);
    F3 r12 = sub(e1, s1), r34 = sub(e2, s2);
    F3 f0 = crs(r13, r14);
    F3 f1 = crs(r14, r24);
    F3 f2 = crs(r24, r23);
    F3 f3 = crs(r23, r13);
    float ss0 = dt(f0,f0), ss1 = dt(f1,f1), ss2 = dt(f2,f2), ss3 = dt(f3,f3);
    float i0 = ss0 > 0.0f ? rsqrtf(ss0) : 0.0f;
    float i1 = ss1 > 0.0f ? rsqrtf(ss1) : 0.0f;
    float i2 = ss2 > 0.0f ? rsqrtf(ss2) : 0.0f;
    float i3 = ss3 > 0.0f ? rsqrtf(ss3) : 0.0f;
    float d01 = fminf(fmaxf(dt(f0,f1) * (i0*i1), -1.0f), 1.0f);
    float d12 = fminf(fmaxf(dt(f1,f2) * (i1*i2), -1.0f), 1.0f);
    float d23 = fminf(fmaxf(dt(f2,f3) * (i2*i3), -1.0f), 1.0f);
    float d30 = fminf(fmaxf(dt(f3,f0) * (i3*i0), -1.0f), 1.0f);
    float tot = asin_fast(d01) + asin_fast(d12) + asin_fast(d23) + asin_fast(d30);
    float sgn = dt(crs(r34, r12), r13);
    float mult = (sgn <= 0.0f) ? -1.0f : 1.0f;
    return mult * tot * 0.07957747154594767f;  // 1/(4*pi)
}

// One block = 4 frames. Stages joints to LDS (coalesced), computes 256 segment-pair
// GLIs per frame (one wave/frame, 4 pairs/lane), reduces to 5x5 path blocks, and
// computes the per-frame xz-bbox overlap flag — all fused.
__global__ void __launch_bounds__(256) k_gli(const float* __restrict__ m1,
                                             const float* __restrict__ m2,
                                             float* __restrict__ gp,
                                             int* __restrict__ flags){
    __shared__ float pts1[4][66];
    __shared__ float pts2[4][66];
    __shared__ float g[4][256];
    int tid = threadIdx.x;
    int frame0 = blockIdx.x * 4;

    // Coalesced staging: 264 consecutive floats from each motion.
    const float* base1 = m1 + (size_t)frame0 * 66;
    const float* base2 = m2 + (size_t)frame0 * 66;
    for (int u = tid; u < 528; u += 256){
        if (u < 264) ((float*)pts1)[u] = base1[u];
        else         ((float*)pts2)[u - 264] = base2[u - 264];
    }
    __syncthreads();

    int w = tid >> 6, lane = tid & 63;
    int n = lane & 15, q = lane >> 4;
    const float* P1 = pts1[w];
    const float* P2 = pts2[w];
    int is2 = c_seg_s[n] * 3, ie2 = c_seg_e[n] * 3;
    F3 s2 = {P2[is2], P2[is2+1], P2[is2+2]};
    F3 e2 = {P2[ie2], P2[ie2+1], P2[ie2+2]};
    #pragma unroll
    for (int k = 0; k < 4; ++k){
        int m = q + 4 * k;
        int is1 = c_seg_s[m] * 3, ie1 = c_seg_e[m] * 3;
        F3 s1 = {P1[is1], P1[is1+1], P1[is1+2]};
        F3 e1 = {P1[ie1], P1[ie1+1], P1[ie1+2]};
        g[w][m * 16 + n] = gli_pair(s1, e1, s2, e2);
    }
    __syncthreads();

    // Threads 0..99: path-pair reduction -> gp laid out [b][pp][f] for coalesced k_vel.
    if (tid < 100){
        int w2 = tid / 25, pp = tid - w2 * 25;
        int i = pp / 5, j = pp - i * 5;
        float s = 0.0f;
        for (int a = 0; a < c_pc[i]; ++a)
            for (int b = 0; b < c_pc[j]; ++b)
                s += g[w2][(c_po[i] + a) * 16 + (c_po[j] + b)];
        int fr = frame0 + w2;
        int bb = fr / FF, f = fr - bb * FF;
        gp[((size_t)bb * 25 + pp) * FF + f] = s;
    }
    // Threads 128..131: per-frame bbox-overlap flag (runs concurrent with reducers).
    else if (tid >= 128 && tid < 132){
        int w2 = tid - 128;
        const float* Q1 = pts1[w2];
        const float* Q2 = pts2[w2];
        float nx1 = 1e30f, xx1 = -1e30f, nz1 = 1e30f, xz1 = -1e30f;
        float nx2 = 1e30f, xx2 = -1e30f, nz2 = 1e30f, xz2 = -1e30f;
        #pragma unroll
        for (int j = 0; j < NJ; ++j){
            float x1 = Q1[j*3+0], z1 = Q1[j*3+2];
            nx1 = fminf(nx1, x1); xx1 = fmaxf(xx1, x1);
            nz1 = fminf(nz1, z1); xz1 = fmaxf(xz1, z1);
            float x2 = Q2[j*3+0], z2 = Q2[j*3+2];
            nx2 = fminf(nx2, x2); xx2 = fmaxf(xx2, x2);
            nz2 = fminf(nz2, z2); xz2 = fmaxf(xz2, z2);
        }
        flags[frame0 + w2] =
            (xx1 >= nx2 && xx2 >= nx1 && xz1 >= nz2 && xz2 >= nz1) ? 1 : 0;
    }
}

// Masked frame-diff, max over 25 path-pairs. One block per batch row; gp is
// [b][pp][f] so every load is lane-contiguous in f.
__global__ void __launch_bounds__(256) k_vel(const float* __restrict__ gp,
                                             const int* __restrict__ flags,
                                             float* __restrict__ out){
    int b = blockIdx.x;
    int f = threadIdx.x;
    if (f >= FF - 1) return;
    const int* fl = flags + b * FF;

    int v0 = fl[f] | fl[f + 1];
    if (f > 0) v0 |= fl[f - 1];
    float mk0 = v0 ? 1.0f : 0.0f;

    int v1 = fl[f] | fl[f + 1];
    if (f + 2 < FF) v1 |= fl[f + 2];
    float mk1 = v1 ? 1.0f : 0.0f;

    const float* gb = gp + (size_t)b * 25 * FF + f;
    float mx = 0.0f;
    #pragma unroll
    for (int p = 0; p < 25; ++p){
        float g0 = gb[p * FF];
        float g1 = gb[p * FF + 1];
        float d = fabsf(g1 * mk1 - g0 * mk0);
        mx = fmaxf(mx, d);
    }
    out[b * (FF - 1) + f] = mx;
}

extern "C" void kernel_launch(void* const* d_in, const int* in_sizes, int n_in,
                              void* d_out, int out_size, void* d_ws, size_t ws_size,
                              hipStream_t stream) {
    const float* m1 = (const float*)d_in[0];
    const float* m2 = (const float*)d_in[1];
    float* gp    = (float*)d_ws;                                   // BB*25*FF floats
    int*   flags = (int*)((char*)d_ws + (size_t)BB * 25 * FF * 4); // NFRM ints
    float* out = (float*)d_out;

    k_gli<<<NFRM / 4, 256, 0, stream>>>(m1, m2, gp, flags);
    k_vel<<<BB, 256, 0, stream>>>(gp, flags, out);
}

// Round 3
// 81.100 us; speedup vs baseline: 1.2575x; 1.0770x over previous
//
#include <hip/hip_runtime.h>
#include <math.h>

// Problem constants: B=64, F=240, J=22, 16 segments, 5 paths.
#define BB 64
#define FF 240
#define NJ 22
#define NFRM (BB * FF)

// Kinematic-chain segment tables.
__constant__ int c_seg_s[16] = {2,5,8, 1,4,7, 3,6,9,12, 14,17,19, 13,16,18};
__constant__ int c_seg_e[16] = {5,8,11, 4,7,10, 6,9,12,15, 17,19,21, 16,18,20};
__constant__ int c_po[5] = {0,3,6,10,13};
__constant__ int c_pc[5] = {3,3,4,3,3};

struct F3 { float x, y, z; };
__device__ __forceinline__ F3 sub(F3 a, F3 b){ return {a.x-b.x, a.y-b.y, a.z-b.z}; }
__device__ __forceinline__ F3 crs(F3 a, F3 b){
    return {fmaf(a.y, b.z, -a.z*b.y), fmaf(a.z, b.x, -a.x*b.z), fmaf(a.x, b.y, -a.y*b.x)};
}
__device__ __forceinline__ float dt(F3 a, F3 b){ return fmaf(a.x, b.x, fmaf(a.y, b.y, a.z*b.z)); }
__device__ __forceinline__ float clamp1(float d){ return fminf(fmaxf(d, -1.0f), 1.0f); }

// Branchless asin, Abramowitz-Stegun 4.4.45 (3-term), |err| <= 6.8e-5 abs.
__device__ __forceinline__ float asin_fast(float d){
    float ax = fabsf(d);
    float p = fmaf(fmaf(fmaf(-0.0187293f, ax, 0.0742610f), ax, -0.2121144f), ax, 1.5707288f);
    float r = 1.57079632679f - sqrtf(1.0f - ax) * p;
    return copysignf(r, d);
}

__device__ __forceinline__ F3 ldp(const float* P, int j){
    return {P[j*3], P[j*3+1], P[j*3+2]};
}

// One block = 4 frames. float4-staged joints in LDS; one wave per frame computes
// 256 segment-pair GLIs (4 pairs/lane, PHASE-PARALLEL across the 4 pairs for ILP),
// reduces to 5x5 path blocks, and computes the per-frame bbox-overlap flag.
__global__ void __launch_bounds__(256) k_gli(const float* __restrict__ m1,
                                             const float* __restrict__ m2,
                                             float* __restrict__ gp,
                                             int* __restrict__ flags){
    __shared__ __align__(16) float pts1[4][66];
    __shared__ __align__(16) float pts2[4][66];
    __shared__ float g[4][256];
    int tid = threadIdx.x;
    int frame0 = blockIdx.x * 4;

    // Staging: 4 frames x 66 floats per motion = 66 float4 per motion.
    if (tid < 132){
        bool first = tid < 66;
        int u = first ? tid : tid - 66;
        const float4* src = first ? (const float4*)(m1 + (size_t)frame0 * 66)
                                  : (const float4*)(m2 + (size_t)frame0 * 66);
        float4* dst = first ? (float4*)&pts1[0][0] : (float4*)&pts2[0][0];
        dst[u] = src[u];
    }
    __syncthreads();

    int w = tid >> 6, lane = tid & 63;
    int n = lane & 15, q = lane >> 4;
    const float* P1 = pts1[w];
    const float* P2 = pts2[w];
    F3 s2 = ldp(P2, c_seg_s[n]);
    F3 e2 = ldp(P2, c_seg_e[n]);
    F3 r34 = sub(e2, s2);

    // Phase 1: geometry for all 4 pairs (independent chains -> ILP).
    float rd01[4], rd12[4], rd23[4], rd30[4];   // raw dots f_i . f_j
    float q01[4], q12[4], q23[4], q30[4];       // |f_i|^2 * |f_j|^2
    float sg[4];                                // sign triple product
    #pragma unroll
    for (int k = 0; k < 4; ++k){
        int m = q + 4 * k;
        F3 s1 = ldp(P1, c_seg_s[m]);
        F3 e1 = ldp(P1, c_seg_e[m]);
        F3 r13 = sub(s2, s1), r14 = sub(e2, s1);
        F3 r23 = sub(s2, e1), r24 = sub(e2, e1);
        F3 r12 = sub(e1, s1);
        F3 f0 = crs(r13, r14);
        F3 f1 = crs(r14, r24);
        F3 f2 = crs(r24, r23);
        F3 f3 = crs(r23, r13);
        float ss0 = dt(f0,f0), ss1 = dt(f1,f1), ss2 = dt(f2,f2), ss3 = dt(f3,f3);
        rd01[k] = dt(f0,f1); rd12[k] = dt(f1,f2);
        rd23[k] = dt(f2,f3); rd30[k] = dt(f3,f0);
        q01[k] = ss0*ss1; q12[k] = ss1*ss2; q23[k] = ss2*ss3; q30[k] = ss3*ss0;
        sg[k] = dt(crs(r34, r12), r13);
    }

    // Phase 2: 16 independent rsqrts (transcendental pipe, back-to-back issue).
    // rsqrt(|fi|^2 |fj|^2) replaces the reference's per-f safe-normalize: if a
    // cross is exactly 0, the raw dot is 0 too -> product 0 -> same result.
    float i01[4], i12[4], i23[4], i30[4];
    #pragma unroll
    for (int k = 0; k < 4; ++k){
        i01[k] = rsqrtf(fmaxf(q01[k], 1e-30f));
        i12[k] = rsqrtf(fmaxf(q12[k], 1e-30f));
        i23[k] = rsqrtf(fmaxf(q23[k], 1e-30f));
        i30[k] = rsqrtf(fmaxf(q30[k], 1e-30f));
    }

    // Phase 3: asins + combine + store.
    #pragma unroll
    for (int k = 0; k < 4; ++k){
        float t = asin_fast(clamp1(rd01[k] * i01[k]))
                + asin_fast(clamp1(rd12[k] * i12[k]))
                + asin_fast(clamp1(rd23[k] * i23[k]))
                + asin_fast(clamp1(rd30[k] * i30[k]));
        float r = (sg[k] <= 0.0f ? -t : t) * 0.07957747154594767f;  // 1/(4*pi)
        int m = q + 4 * k;
        g[w][m * 16 + n] = r;
    }
    __syncthreads();

    // Threads 0..99: path-pair reduction -> gp laid out [b][pp][f] for coalesced k_vel.
    if (tid < 100){
        int w2 = tid / 25, pp = tid - w2 * 25;
        int i = pp / 5, j = pp - i * 5;
        float s = 0.0f;
        for (int a = 0; a < c_pc[i]; ++a)
            for (int b = 0; b < c_pc[j]; ++b)
                s += g[w2][(c_po[i] + a) * 16 + (c_po[j] + b)];
        int fr = frame0 + w2;
        int bb = fr / FF, f = fr - bb * FF;
        gp[((size_t)bb * 25 + pp) * FF + f] = s;
    }
    // Threads 128..131: per-frame bbox-overlap flag.
    else if (tid >= 128 && tid < 132){
        int w2 = tid - 128;
        const float* Q1 = pts1[w2];
        const float* Q2 = pts2[w2];
        float nx1 = 1e30f, xx1 = -1e30f, nz1 = 1e30f, xz1 = -1e30f;
        float nx2 = 1e30f, xx2 = -1e30f, nz2 = 1e30f, xz2 = -1e30f;
        #pragma unroll
        for (int j = 0; j < NJ; ++j){
            float x1 = Q1[j*3+0], z1 = Q1[j*3+2];
            nx1 = fminf(nx1, x1); xx1 = fmaxf(xx1, x1);
            nz1 = fminf(nz1, z1); xz1 = fmaxf(xz1, z1);
            float x2 = Q2[j*3+0], z2 = Q2[j*3+2];
            nx2 = fminf(nx2, x2); xx2 = fmaxf(xx2, x2);
            nz2 = fminf(nz2, z2); xz2 = fmaxf(xz2, z2);
        }
        flags[frame0 + w2] =
            (xx1 >= nx2 && xx2 >= nx1 && xz1 >= nz2 && xz2 >= nz1) ? 1 : 0;
    }
}

// Masked frame-diff, max over 25 path-pairs. gp is [b][pp][f]: lane-contiguous in f.
__global__ void __launch_bounds__(256) k_vel(const float* __restrict__ gp,
                                             const int* __restrict__ flags,
                                             float* __restrict__ out){
    int b = blockIdx.x;
    int f = threadIdx.x;
    if (f >= FF - 1) return;
    const int* fl = flags + b * FF;

    int v0 = fl[f] | fl[f + 1];
    if (f > 0) v0 |= fl[f - 1];
    float mk0 = v0 ? 1.0f : 0.0f;

    int v1 = fl[f] | fl[f + 1];
    if (f + 2 < FF) v1 |= fl[f + 2];
    float mk1 = v1 ? 1.0f : 0.0f;

    const float* gb = gp + (size_t)b * 25 * FF + f;
    float mx = 0.0f;
    #pragma unroll
    for (int p = 0; p < 25; ++p){
        float g0 = gb[p * FF];
        float g1 = gb[p * FF + 1];
        float d = fabsf(g1 * mk1 - g0 * mk0);
        mx = fmaxf(mx, d);
    }
    out[b * (FF - 1) + f] = mx;
}

extern "C" void kernel_launch(void* const* d_in, const int* in_sizes, int n_in,
                              void* d_out, int out_size, void* d_ws, size_t ws_size,
                              hipStream_t stream) {
    const float* m1 = (const float*)d_in[0];
    const float* m2 = (const float*)d_in[1];
    float* gp    = (float*)d_ws;                                   // BB*25*FF floats
    int*   flags = (int*)((char*)d_ws + (size_t)BB * 25 * FF * 4); // NFRM ints
    float* out = (float*)d_out;

    k_gli<<<NFRM / 4, 256, 0, stream>>>(m1, m2, gp, flags);
    k_vel<<<BB, 256, 0, stream>>>(gp, flags, out);
}

// Round 4
// 80.966 us; speedup vs baseline: 1.2596x; 1.0016x over previous
//
#include <hip/hip_runtime.h>
#include <math.h>

// Problem constants: B=64, F=240, J=22, 16 segments, 5 paths.
#define BB 64
#define FF 240
#define NJ 22
#define NFRM (BB * FF)

// Segment joint tables bit-packed 5 bits/entry into constexpr immediates
// (a __constant__ array indexed by a per-lane value forces a per-lane
// global_load; packed immediates decode in ~4 VALU ops instead).
#define PK8(a0,a1,a2,a3,a4,a5,a6,a7) \
  (  (unsigned long long)(a0)        | ((unsigned long long)(a1) << 5)  \
   | ((unsigned long long)(a2) << 10)| ((unsigned long long)(a3) << 15) \
   | ((unsigned long long)(a4) << 20)| ((unsigned long long)(a5) << 25) \
   | ((unsigned long long)(a6) << 30)| ((unsigned long long)(a7) << 35) )
static constexpr unsigned long long SEG_S_LO = PK8(2,5,8,1,4,7,3,6);
static constexpr unsigned long long SEG_S_HI = PK8(9,12,14,17,19,13,16,18);
static constexpr unsigned long long SEG_E_LO = PK8(5,8,11,4,7,10,6,9);
static constexpr unsigned long long SEG_E_HI = PK8(12,15,17,19,21,16,18,20);
// Path offset/count tables, 5 bits/entry.
static constexpr unsigned PO_PK = 0u | (3u<<5) | (6u<<10) | (10u<<15) | (13u<<20);
static constexpr unsigned PC_PK = 3u | (3u<<5) | (4u<<10) | (3u<<15)  | (3u<<20);

struct F3 { float x, y, z; };
__device__ __forceinline__ F3 sub(F3 a, F3 b){ return {a.x-b.x, a.y-b.y, a.z-b.z}; }
__device__ __forceinline__ F3 crs(F3 a, F3 b){
    return {fmaf(a.y, b.z, -a.z*b.y), fmaf(a.z, b.x, -a.x*b.z), fmaf(a.x, b.y, -a.y*b.x)};
}
__device__ __forceinline__ float dt(F3 a, F3 b){ return fmaf(a.x, b.x, fmaf(a.y, b.y, a.z*b.z)); }
__device__ __forceinline__ float clamp1(float d){ return fminf(fmaxf(d, -1.0f), 1.0f); }

// Branchless asin, Abramowitz-Stegun 4.4.45 (3-term), |err| <= 6.8e-5 abs.
__device__ __forceinline__ float asin_fast(float d){
    float ax = fabsf(d);
    float p = fmaf(fmaf(fmaf(-0.0187293f, ax, 0.0742610f), ax, -0.2121144f), ax, 1.5707288f);
    float r = 1.57079632679f - sqrtf(1.0f - ax) * p;
    return copysignf(r, d);
}

// One block = 4 frames. Pipeline:
//   stage raw joints (float4, coalesced) -> build LDS segment-endpoint table
//   -> one wave/frame computes 256 pair GLIs (4/lane, phase-parallel)
//   -> 5x5 path reduction + bbox flag.
__global__ void __launch_bounds__(256) k_gli(const float* __restrict__ m1,
                                             const float* __restrict__ m2,
                                             float* __restrict__ gp,
                                             int* __restrict__ flags){
    __shared__ __align__(16) float pts[2][4][66];     // [motion][frame][joint*3+c]
    __shared__ __align__(16) float seg[4][2][16][12]; // [frame][motion][seg][sx sy sz ex ey ez pad..]
    __shared__ float g[4][256];
    int tid = threadIdx.x;
    int frame0 = blockIdx.x * 4;

    // Stage: 66 float4 per motion (264 consecutive floats, 16B-aligned).
    if (tid < 132){
        bool first = tid < 66;
        int u = first ? tid : tid - 66;
        const float4* src = first ? (const float4*)(m1 + (size_t)frame0 * 66)
                                  : (const float4*)(m2 + (size_t)frame0 * 66);
        ((float4*)pts)[(first ? 0 : 66) + u] = src[u];
    }
    __syncthreads();

    // Build segment table: 128 threads, one (frame, motion, seg) entry each.
    if (tid < 128){
        int m = tid & 15, mot = (tid >> 4) & 1, w0 = tid >> 5;
        unsigned long long ps = (m < 8) ? SEG_S_LO : SEG_S_HI;
        unsigned long long pe = (m < 8) ? SEG_E_LO : SEG_E_HI;
        int sh = (m & 7) * 5;
        int js = (int)((ps >> sh) & 31);
        int je = (int)((pe >> sh) & 31);
        const float* P = pts[mot][w0];
        float* dst = &seg[w0][mot][m][0];
        float4 a = {P[js*3], P[js*3+1], P[js*3+2], P[je*3]};
        float2 b = {P[je*3+1], P[je*3+2]};
        *(float4*)dst = a;
        *(float2*)(dst + 4) = b;
    }
    __syncthreads();

    int w = tid >> 6, lane = tid & 63;
    int n = lane & 15, q = lane >> 4;

    // Segment n of motion2: one b128 + one b64 read.
    float4 sa = *(const float4*)&seg[w][1][n][0];
    float2 sb = *(const float2*)&seg[w][1][n][4];
    F3 s2 = {sa.x, sa.y, sa.z};
    F3 e2 = {sa.w, sb.x, sb.y};

    // Phase 1: geometry for 4 pairs (independent chains -> ILP).
    float rd01[4], rd12[4], rd23[4], rd30[4];
    float q01[4], q12[4], q23[4], q30[4];
    float sg[4];                       // f3 . r14  (== -reference_sign)
    #pragma unroll
    for (int k = 0; k < 4; ++k){
        int m = q + 4 * k;
        float4 ta = *(const float4*)&seg[w][0][m][0];
        float2 tb = *(const float2*)&seg[w][0][m][4];
        F3 s1 = {ta.x, ta.y, ta.z};
        F3 e1 = {ta.w, tb.x, tb.y};
        F3 r13 = sub(s2, s1), r14 = sub(e2, s1);
        F3 r23 = sub(s2, e1), r24 = sub(e2, e1);
        F3 f0 = crs(r13, r14);
        F3 f1 = crs(r14, r24);
        F3 f2 = crs(r24, r23);
        F3 f3 = crs(r23, r13);
        float ss0 = dt(f0,f0), ss1 = dt(f1,f1), ss2 = dt(f2,f2), ss3 = dt(f3,f3);
        rd01[k] = dt(f0,f1); rd12[k] = dt(f1,f2);
        rd23[k] = dt(f2,f3); rd30[k] = dt(f3,f0);
        q01[k] = ss0*ss1; q12[k] = ss1*ss2; q23[k] = ss2*ss3; q30[k] = ss3*ss0;
        // (r34 x r12) . r13 == -(f3 . r14): reuse f3, skip the 5th cross.
        sg[k] = dt(f3, r14);
    }

    // Phase 2: 16 independent rsqrts.
    float i01[4], i12[4], i23[4], i30[4];
    #pragma unroll
    for (int k = 0; k < 4; ++k){
        i01[k] = rsqrtf(fmaxf(q01[k], 1e-30f));
        i12[k] = rsqrtf(fmaxf(q12[k], 1e-30f));
        i23[k] = rsqrtf(fmaxf(q23[k], 1e-30f));
        i30[k] = rsqrtf(fmaxf(q30[k], 1e-30f));
    }

    // Phase 3: asins + combine + store.
    #pragma unroll
    for (int k = 0; k < 4; ++k){
        float t = asin_fast(clamp1(rd01[k] * i01[k]))
                + asin_fast(clamp1(rd12[k] * i12[k]))
                + asin_fast(clamp1(rd23[k] * i23[k]))
                + asin_fast(clamp1(rd30[k] * i30[k]));
        // ref: mult = (sign<=0) ? -1 : 1, sign = -sg  =>  negate when sg >= 0.
        float r = (sg[k] >= 0.0f ? -t : t) * 0.07957747154594767f;  // 1/(4*pi)
        int m = q + 4 * k;
        g[w][m * 16 + n] = r;
    }
    __syncthreads();

    // Threads 0..99: path-pair reduction -> gp[b][pp][f] (coalesced for k_vel).
    if (tid < 100){
        int w2 = tid / 25, pp = tid - w2 * 25;
        int i = pp / 5, j = pp - i * 5;
        int poi = (int)((PO_PK >> (i*5)) & 31), pci = (int)((PC_PK >> (i*5)) & 31);
        int poj = (int)((PO_PK >> (j*5)) & 31), pcj = (int)((PC_PK >> (j*5)) & 31);
        float s = 0.0f;
        for (int a = 0; a < pci; ++a)
            for (int b = 0; b < pcj; ++b)
                s += g[w2][(poi + a) * 16 + (poj + b)];
        int fr = frame0 + w2;
        int bb = fr / FF, f = fr - bb * FF;
        gp[((size_t)bb * 25 + pp) * FF + f] = s;
    }
    // Threads 128..131: per-frame bbox-overlap flag.
    else if (tid >= 128 && tid < 132){
        int w2 = tid - 128;
        const float* Q1 = pts[0][w2];
        const float* Q2 = pts[1][w2];
        float nx1 = 1e30f, xx1 = -1e30f, nz1 = 1e30f, xz1 = -1e30f;
        float nx2 = 1e30f, xx2 = -1e30f, nz2 = 1e30f, xz2 = -1e30f;
        #pragma unroll
        for (int j = 0; j < NJ; ++j){
            float x1 = Q1[j*3+0], z1 = Q1[j*3+2];
            nx1 = fminf(nx1, x1); xx1 = fmaxf(xx1, x1);
            nz1 = fminf(nz1, z1); xz1 = fmaxf(xz1, z1);
            float x2 = Q2[j*3+0], z2 = Q2[j*3+2];
            nx2 = fminf(nx2, x2); xx2 = fmaxf(xx2, x2);
            nz2 = fminf(nz2, z2); xz2 = fmaxf(xz2, z2);
        }
        flags[frame0 + w2] =
            (xx1 >= nx2 && xx2 >= nx1 && xz1 >= nz2 && xz2 >= nz1) ? 1 : 0;
    }
}

// Masked frame-diff, max over 25 path-pairs. gp is [b][pp][f]: lane-contiguous in f.
__global__ void __launch_bounds__(256) k_vel(const float* __restrict__ gp,
                                             const int* __restrict__ flags,
                                             float* __restrict__ out){
    int b = blockIdx.x;
    int f = threadIdx.x;
    if (f >= FF - 1) return;
    const int* fl = flags + b * FF;

    int v0 = fl[f] | fl[f + 1];
    if (f > 0) v0 |= fl[f - 1];
    float mk0 = v0 ? 1.0f : 0.0f;

    int v1 = fl[f] | fl[f + 1];
    if (f + 2 < FF) v1 |= fl[f + 2];
    float mk1 = v1 ? 1.0f : 0.0f;

    const float* gb = gp + (size_t)b * 25 * FF + f;
    float mx = 0.0f;
    #pragma unroll
    for (int p = 0; p < 25; ++p){
        float g0 = gb[p * FF];
        float g1 = gb[p * FF + 1];
        float d = fabsf(g1 * mk1 - g0 * mk0);
        mx = fmaxf(mx, d);
    }
    out[b * (FF - 1) + f] = mx;
}

extern "C" void kernel_launch(void* const* d_in, const int* in_sizes, int n_in,
                              void* d_out, int out_size, void* d_ws, size_t ws_size,
                              hipStream_t stream) {
    const float* m1 = (const float*)d_in[0];
    const float* m2 = (const float*)d_in[1];
    float* gp    = (float*)d_ws;                                   // BB*25*FF floats
    int*   flags = (int*)((char*)d_ws + (size_t)BB * 25 * FF * 4); // NFRM ints
    float* out = (float*)d_out;

    k_gli<<<NFRM / 4, 256, 0, stream>>>(m1, m2, gp, flags);
    k_vel<<<BB, 256, 0, stream>>>(gp, flags, out);
}